// Round 11
// baseline (105.317 us; speedup 1.0000x reference)
//
#include <hip/hip_runtime.h>

constexpr int N    = 128;
constexpr int C    = 2048;
constexpr int KP   = 4;
constexpr int KN   = 508;
constexpr int K    = 512;      // KP + KN
constexpr int NK   = N * K;    // 65536 gathers
constexpr int NC   = 50000;    // memory bank rows
constexpr int NINL = 3;        // pairs inlined in the slot header (int4: cnt,p0,p1,p2)
constexpr int NOVF = 13;       // extra pairs per idx in ovf  (MAXD = 16 total)
constexpr int MAXD = NINL + NOVF;
constexpr int SCAP = 2048;     // spill capacity (P(cnt>16) ~ 1e-9; correctness path)

// ws layout (ints):
//   memset region: slot[NC*4] | wcount | scount          ( (NC*4+2)*4 bytes )
//   ovf[NC*NOVF] | work[NC] | spill[SCAP] | row_loss(f32)[N]
constexpr size_t MEMSET_INTS = (size_t)NC * 4 + 2;

__device__ __forceinline__ int gather_idx(const int* pos_idx, const int* neg_idx, int n, int k) {
    return (k < KP) ? pos_idx[n * KP + k] : neg_idx[n * KN + (k - KP)];
}

// One atomic + <=1 store per gather. Slot header int4 {cnt,p0,p1,p2} lives on
// one 16B beat -> main kernel gets cnt AND 3 pairs with a single load.
__global__ __launch_bounds__(256) void build_kernel(
    const int* __restrict__ pos_idx, const int* __restrict__ neg_idx,
    int* __restrict__ slot, int* __restrict__ wcount, int* __restrict__ scount,
    int* __restrict__ ovf, int* __restrict__ work, int* __restrict__ spill)
{
    const int t = blockIdx.x * 256 + threadIdx.x;   // < NK
    const int n = t >> 9, k = t & (K - 1);
    const int idx = gather_idx(pos_idx, neg_idx, n, k);
    const int packed = (n << 9) | k;                 // 16 bits
    const int p = atomicAdd(&slot[idx * 4], 1);
    if (p == 0) {
        work[atomicAdd(wcount, 1)] = idx;
    }
    if (p < NINL) {
        slot[idx * 4 + 1 + p] = packed;
    } else if (p < MAXD) {
        ovf[idx * NOVF + (p - NINL)] = packed;
    } else {
        const int s = atomicAdd(scount, 1);
        if (s < SCAP) spill[s] = (idx << 16) | packed;
    }
}

// Persistent waves: 4096 waves loop over the compact worklist. Per item:
// one int4 slot load (cnt + 3 pairs), 8 KB M row -> registers ONCE, then
// r2-shaped serves against L2-resident inputs rows. M HBM = unique rows only.
__global__ __launch_bounds__(256) void gemv_dedup_kernel(
    const float* __restrict__ inputs,
    const float* __restrict__ M,
    const int*   __restrict__ slot,
    const int*   __restrict__ ovf,
    const int*   __restrict__ work,
    const int*   __restrict__ wcount,
    const int*   __restrict__ scount,
    const int*   __restrict__ spill,
    float*       __restrict__ logits)
{
    const int lane = threadIdx.x & 63;
    const int wid  = (blockIdx.x * 256 + threadIdx.x) >> 6;
    const int nw   = gridDim.x * 4;
    const int W    = *wcount;

    const float4* __restrict__ A = reinterpret_cast<const float4*>(inputs);

    int next_idx = (wid < W) ? work[wid] : 0;

    for (int g = wid; g < W; g += nw) {
        const int idx = next_idx;
        if (g + nw < W) next_idx = work[g + nw];          // prefetch next item

        const int4 s = *reinterpret_cast<const int4*>(&slot[idx * 4]);
        const int cnt = s.x;

        const float4* __restrict__ b = reinterpret_cast<const float4*>(M + (size_t)idx * C);
        float4 mrow[8];
        #pragma unroll
        for (int i = 0; i < 8; ++i) mrow[i] = b[i * 64 + lane];   // 8 KB, coalesced, once

        auto serve = [&](int packed) {
            const float4* __restrict__ a = A + (size_t)(packed >> 9) * (C / 4);
            float acc = 0.f;
            #pragma unroll
            for (int i = 0; i < 8; ++i) {
                const float4 av = a[i * 64 + lane];
                acc = fmaf(mrow[i].x, av.x, acc);
                acc = fmaf(mrow[i].y, av.y, acc);
                acc = fmaf(mrow[i].z, av.z, acc);
                acc = fmaf(mrow[i].w, av.w, acc);
            }
            #pragma unroll
            for (int off = 32; off > 0; off >>= 1)
                acc += __shfl_down(acc, off, 64);
            if (lane == 0)
                logits[(packed >> 9) * K + (packed & (K - 1))] = acc;
        };

        serve(s.y);
        if (cnt > 1) serve(s.z);
        if (cnt > 2) serve(s.w);
        const int lim = cnt < MAXD ? cnt : MAXD;
        for (int j = NINL; j < lim; ++j)
            serve(ovf[idx * NOVF + (j - NINL)]);
        if (cnt > MAXD) {                                  // ~never; correctness path
            const int sc = min(*scount, SCAP);
            for (int i = 0; i < sc; ++i) {
                const int e = spill[i];
                if ((e >> 16) == idx) serve(e & 0xFFFF);
            }
        }
    }
}

__global__ __launch_bounds__(512) void softmax_loss_kernel(
    const float* __restrict__ logits,
    const float* __restrict__ cof,
    float*       __restrict__ row_loss)
{
    __shared__ float red[8];
    __shared__ float xs[KP];
    const int n    = blockIdx.x;
    const int t    = threadIdx.x;
    const int wid  = t >> 6;
    const int lane = t & 63;

    float x = logits[n * K + t];

    float m = x;
    #pragma unroll
    for (int off = 1; off < 64; off <<= 1)
        m = fmaxf(m, __shfl_xor(m, off, 64));
    if (lane == 0) red[wid] = m;
    __syncthreads();
    float bm = red[0];
    #pragma unroll
    for (int i = 1; i < 8; ++i) bm = fmaxf(bm, red[i]);

    float s = expf(x - bm);
    #pragma unroll
    for (int off = 1; off < 64; off <<= 1)
        s += __shfl_xor(s, off, 64);
    __syncthreads();
    if (lane == 0) red[wid] = s;
    if (t < KP) xs[t] = x;
    __syncthreads();

    if (t == 0) {
        float bs = 0.f;
        #pragma unroll
        for (int i = 0; i < 8; ++i) bs += red[i];
        const float logZ = bm + logf(bs);
        float acc = 0.f;
        #pragma unroll
        for (int j = 0; j < KP; ++j)
            acc += cof[j] * (xs[j] - logZ);
        row_loss[n] = acc;
    }
}

__global__ __launch_bounds__(128) void loss_reduce_kernel(
    const float* __restrict__ row_loss,
    float*       __restrict__ out)
{
    const int t = threadIdx.x;
    float v = row_loss[t];
    #pragma unroll
    for (int off = 1; off < 64; off <<= 1)
        v += __shfl_xor(v, off, 64);
    __shared__ float red[2];
    if ((t & 63) == 0) red[t >> 6] = v;
    __syncthreads();
    if (t == 0) out[0] = -(red[0] + red[1]) / (float)N;
}

// Fallback (round-2 structure) if ws is too small.
__global__ __launch_bounds__(256) void logits_kernel(
    const float* __restrict__ inputs,
    const int*   __restrict__ pos_idx,
    const int*   __restrict__ neg_idx,
    const float* __restrict__ M,
    float*       __restrict__ logits)
{
    const int wave = threadIdx.x >> 6;
    const int lane = threadIdx.x & 63;
    const int n    = blockIdx.y;
    const int k    = (blockIdx.x << 2) + wave;

    const int idx = (k < KP) ? pos_idx[n * KP + k]
                             : neg_idx[n * KN + (k - KP)];

    const float4* __restrict__ a = reinterpret_cast<const float4*>(inputs + (size_t)n * C);
    const float4* __restrict__ b = reinterpret_cast<const float4*>(M + (size_t)idx * C);

    float acc = 0.f;
    #pragma unroll
    for (int i = 0; i < C / (4 * 64); ++i) {
        float4 av = a[i * 64 + lane];
        float4 bv = b[i * 64 + lane];
        acc = fmaf(av.x, bv.x, acc);
        acc = fmaf(av.y, bv.y, acc);
        acc = fmaf(av.z, bv.z, acc);
        acc = fmaf(av.w, bv.w, acc);
    }
    #pragma unroll
    for (int off = 32; off > 0; off >>= 1)
        acc += __shfl_down(acc, off, 64);
    if (lane == 0) logits[n * K + k] = acc;
}

extern "C" void kernel_launch(void* const* d_in, const int* in_sizes, int n_in,
                              void* d_out, int out_size, void* d_ws, size_t ws_size,
                              hipStream_t stream) {
    const float* inputs  = (const float*)d_in[0];
    const int*   pos_idx = (const int*)d_in[1];
    const int*   neg_idx = (const int*)d_in[2];
    const float* cof     = (const float*)d_in[3];
    const float* M       = (const float*)d_in[4];

    float* out    = (float*)d_out;
    float* logits = out + 1;            // d_out = [loss(1), logits(128*512)]

    const size_t need = (MEMSET_INTS + (size_t)NC * NOVF + NC + SCAP + N) * 4;
    if (ws_size >= need) {
        int*   slot     = (int*)d_ws;                       // NC*4 ints
        int*   wcount   = slot + (size_t)NC * 4;
        int*   scount   = wcount + 1;
        int*   ovf      = scount + 1;                       // NC*NOVF
        int*   work     = ovf + (size_t)NC * NOVF;          // NC
        int*   spill    = work + NC;                        // SCAP
        float* row_loss = (float*)(spill + SCAP);           // N

        hipMemsetAsync(slot, 0, MEMSET_INTS * 4, stream);
        build_kernel<<<NK / 256, 256, 0, stream>>>(pos_idx, neg_idx, slot, wcount, scount,
                                                   ovf, work, spill);
        gemv_dedup_kernel<<<1024, 256, 0, stream>>>(inputs, M, slot, ovf, work,
                                                    wcount, scount, spill, logits);
        softmax_loss_kernel<<<N, K, 0, stream>>>(logits, cof, row_loss);
        loss_reduce_kernel<<<1, N, 0, stream>>>(row_loss, out);
    } else {
        float* row_loss = (float*)d_ws;
        logits_kernel<<<dim3(K / 4, N), 256, 0, stream>>>(inputs, pos_idx, neg_idx, M, logits);
        softmax_loss_kernel<<<N, K, 0, stream>>>(logits, cof, row_loss);
        loss_reduce_kernel<<<1, N, 0, stream>>>(row_loss, out);
    }
}

// Round 12
// 83.260 us; speedup vs baseline: 1.2649x; 1.2649x over previous
//
#include <hip/hip_runtime.h>

constexpr int N  = 128;
constexpr int C  = 2048;
constexpr int KP = 4;
constexpr int KN = 508;
constexpr int K  = 512;   // KP + KN

// One wave (64 lanes) computes one logit: dot(inputs[n], M[idx]) over C=2048.
// 4 waves per 256-thread block; blockIdx.y = n so inputs row is cache-hot.
//
// Measured (r2): 82.3 µs total, logits kernel ~6.6 TB/s on 537 MB raw gather
// traffic = achievable HBM BW (harness fill kernel measures 82-87% peak).
// Dedup/sort/bucket variants (r3-r11: 84-118 µs) all lost: their ~43%
// traffic saving is outweighed by pre-pass atomics, extra graph nodes,
// dependent-load chains, and lost L1 input locality. This is the roofline
// structure for this op on MI355X.
__global__ __launch_bounds__(256) void logits_kernel(
    const float* __restrict__ inputs,
    const int*   __restrict__ pos_idx,
    const int*   __restrict__ neg_idx,
    const float* __restrict__ M,
    float*       __restrict__ logits)
{
    const int wave = threadIdx.x >> 6;
    const int lane = threadIdx.x & 63;
    const int n    = blockIdx.y;
    const int k    = (blockIdx.x << 2) + wave;

    const int idx = (k < KP) ? pos_idx[n * KP + k]
                             : neg_idx[n * KN + (k - KP)];

    const float4* __restrict__ a = reinterpret_cast<const float4*>(inputs + (size_t)n * C);
    const float4* __restrict__ b = reinterpret_cast<const float4*>(M + (size_t)idx * C);

    float acc = 0.f;
    #pragma unroll
    for (int i = 0; i < C / (4 * 64); ++i) {   // 8 iterations, 16 B/lane each
        float4 av = a[i * 64 + lane];
        float4 bv = b[i * 64 + lane];
        acc = fmaf(av.x, bv.x, acc);
        acc = fmaf(av.y, bv.y, acc);
        acc = fmaf(av.z, bv.z, acc);
        acc = fmaf(av.w, bv.w, acc);
    }

    #pragma unroll
    for (int off = 32; off > 0; off >>= 1)
        acc += __shfl_down(acc, off, 64);

    if (lane == 0) logits[n * K + k] = acc;
}

// One block per row n: log-softmax denominator over K=512, then the
// weighted positive-logit partial loss for this row (deterministic).
__global__ __launch_bounds__(512) void softmax_loss_kernel(
    const float* __restrict__ logits,
    const float* __restrict__ cof,
    float*       __restrict__ row_loss)
{
    __shared__ float red[8];
    __shared__ float xs[KP];
    const int n    = blockIdx.x;
    const int t    = threadIdx.x;
    const int wid  = t >> 6;
    const int lane = t & 63;

    float x = logits[n * K + t];

    // block max
    float m = x;
    #pragma unroll
    for (int off = 1; off < 64; off <<= 1)
        m = fmaxf(m, __shfl_xor(m, off, 64));
    if (lane == 0) red[wid] = m;
    __syncthreads();
    float bm = red[0];
    #pragma unroll
    for (int i = 1; i < 8; ++i) bm = fmaxf(bm, red[i]);

    // block sum of exp
    float s = expf(x - bm);
    #pragma unroll
    for (int off = 1; off < 64; off <<= 1)
        s += __shfl_xor(s, off, 64);
    __syncthreads();
    if (lane == 0) red[wid] = s;
    if (t < KP) xs[t] = x;
    __syncthreads();

    if (t == 0) {
        float bs = 0.f;
        #pragma unroll
        for (int i = 0; i < 8; ++i) bs += red[i];
        const float logZ = bm + logf(bs);
        float acc = 0.f;
        #pragma unroll
        for (int j = 0; j < KP; ++j)
            acc += cof[j] * (xs[j] - logZ);
        row_loss[n] = acc;   // = sum_j cof[j] * logp[n, j]
    }
}

// Single block: deterministic fixed-order reduction of 128 row losses.
__global__ __launch_bounds__(128) void loss_reduce_kernel(
    const float* __restrict__ row_loss,
    float*       __restrict__ out)
{
    const int t = threadIdx.x;
    float v = row_loss[t];
    #pragma unroll
    for (int off = 1; off < 64; off <<= 1)
        v += __shfl_xor(v, off, 64);
    __shared__ float red[2];
    if ((t & 63) == 0) red[t >> 6] = v;
    __syncthreads();
    if (t == 0) out[0] = -(red[0] + red[1]) / (float)N;
}

extern "C" void kernel_launch(void* const* d_in, const int* in_sizes, int n_in,
                              void* d_out, int out_size, void* d_ws, size_t ws_size,
                              hipStream_t stream) {
    const float* inputs  = (const float*)d_in[0];
    const int*   pos_idx = (const int*)d_in[1];
    const int*   neg_idx = (const int*)d_in[2];
    const float* cof     = (const float*)d_in[3];
    const float* M       = (const float*)d_in[4];

    float* out      = (float*)d_out;
    float* logits   = out + 1;          // d_out = [loss(1), logits(128*512)]
    float* row_loss = (float*)d_ws;     // 128 floats of scratch

    logits_kernel<<<dim3(K / 4, N), 256, 0, stream>>>(inputs, pos_idx, neg_idx, M, logits);
    softmax_loss_kernel<<<N, K, 0, stream>>>(logits, cof, row_loss);
    loss_reduce_kernel<<<1, N, 0, stream>>>(row_loss, out);
}